// Round 1
// baseline (811.904 us; speedup 1.0000x reference)
//
#include <hip/hip_runtime.h>
#include <hip/hip_bf16.h>
#include <math.h>

// TreeLSTM on MI355X.
// Key ideas:
//  - xg = emb[ids] @ W collapses to a 4x64x256 table (V=64).
//  - per-level [hl|hr] A-matrix is h_prev reinterpreted as (B*n, 512): zero movement.
//  - bf16 MFMA 16x16x32, fp32 accum; 5 waves/block = 5 gates; fused gate epilogue via LDS.

typedef __bf16 bf16x8 __attribute__((ext_vector_type(8)));
typedef float  f32x4  __attribute__((ext_vector_type(4)));

__global__ void xg_prep(const float* __restrict__ emb, const float* __restrict__ W,
                        const float* __restrict__ bW, float* __restrict__ xg) {
    // block = (g,v): g = bx>>6, v = bx&63 ; thread k in [0,256)
    int g = blockIdx.x >> 6, v = blockIdx.x & 63, k = threadIdx.x;
    __shared__ float e[256];
    e[k] = emb[v * 256 + k];
    __syncthreads();
    float s = bW[g * 256 + k];
    const float* Wg = W + g * 65536 + k;   // W[g][i][k], stride 256 over i
#pragma unroll 4
    for (int i = 0; i < 256; i++) s += e[i] * Wg[i * 256];
    xg[(g * 64 + v) * 256 + k] = s;
}

__global__ void bt_prep(const float* __restrict__ U, __bf16* __restrict__ Bt) {
    // Bt[g][col][kk] (kk contiguous, 512 = [U[g][0][:,col] ; U[g][1][:,col]])
    int idx = blockIdx.x * 256 + threadIdx.x;   // < 5*256*512 = 655360
    int g   = idx >> 17;
    int r   = idx & 131071;
    int col = r >> 9;
    int kk  = r & 511;
    int s   = kk >> 8;
    int hh  = kk & 255;
    Bt[idx] = (__bf16)U[((g * 2 + s) * 256 + hh) * 256 + col];
}

__global__ void leaf_kernel(const int* __restrict__ ids, const float* __restrict__ xg,
                            __bf16* __restrict__ h, __bf16* __restrict__ c) {
    int r = blockIdx.x;        // (b*1024 + j), 65536 rows
    int col = threadIdx.x;     // 0..255
    int b = r >> 10, j = r & 1023;
    int id = ids[b * 2046 + 1022 + j];
    // leaves: pre = xg only; i uses xg[1], o uses xg[2], u uses xg[3]; cl=cr=0
    float x1 = xg[(64  + id) * 256 + col];
    float x2 = xg[(128 + id) * 256 + col];
    float x3 = xg[(192 + id) * 256 + col];
    float ig = 1.f / (1.f + expf(-x1));
    float og = 1.f / (1.f + expf(-x2));
    float ug = tanhf(x3);
    float cv = ig * ug;
    float hv = og * tanhf(cv);
    h[r * 256 + col] = (__bf16)hv;
    c[r * 256 + col] = (__bf16)cv;
}

// Block: 320 threads = 5 waves, wave g computes gate g over a 32-row x 64-col tile.
// A = h_prev as (M,512) bf16 row-major (K contiguous).
// Bt = (5*256, 512) bf16, N-major, K contiguous.
__global__ __launch_bounds__(320) void level_kernel(
    const __bf16* __restrict__ A, const __bf16* __restrict__ Cprev,
    const __bf16* __restrict__ Bt, const float* __restrict__ xg,
    const int* __restrict__ ids, __bf16* __restrict__ h_out,
    __bf16* __restrict__ c_out, float* __restrict__ rh_out, int lev) {
    __shared__ float lds[5 * 32 * 64];   // 40 KB: activated gates
    const int g    = threadIdx.x >> 6;   // gate 0..4
    const int lane = threadIdx.x & 63;
    const int lr   = lane & 15;          // frag row/col within 16
    const int q    = lane >> 4;          // quad 0..3
    const long rowblk = (long)blockIdx.x * 32;
    const int  colblk = blockIdx.y * 64;

    const __bf16* Ap = A + (rowblk + lr) * 512 + q * 8;
    const __bf16* Bp = Bt + (long)(g * 256 + colblk + lr) * 512 + q * 8;

    f32x4 acc[2][4];
#pragma unroll
    for (int mt = 0; mt < 2; mt++)
#pragma unroll
        for (int nt = 0; nt < 4; nt++) acc[mt][nt] = (f32x4){0.f, 0.f, 0.f, 0.f};

    for (int kk = 0; kk < 512; kk += 32) {
        bf16x8 af[2], bfr[4];
#pragma unroll
        for (int mt = 0; mt < 2; mt++)
            af[mt] = *(const bf16x8*)(Ap + (long)mt * 16 * 512 + kk);
#pragma unroll
        for (int nt = 0; nt < 4; nt++)
            bfr[nt] = *(const bf16x8*)(Bp + (long)nt * 16 * 512 + kk);
#pragma unroll
        for (int mt = 0; mt < 2; mt++)
#pragma unroll
            for (int nt = 0; nt < 4; nt++)
                acc[mt][nt] = __builtin_amdgcn_mfma_f32_16x16x32_bf16(
                    af[mt], bfr[nt], acc[mt][nt], 0, 0, 0);
    }

    // epilogue pt 1: add xg, activate, stash in LDS.
    const int n = 1 << lev;
    const int gmg = (g < 2) ? 0 : (g - 1);   // gate_map = [0,0,1,2,3]
#pragma unroll
    for (int mt = 0; mt < 2; mt++) {
#pragma unroll
        for (int v = 0; v < 4; v++) {
            int lrow = mt * 16 + q * 4 + v;           // C layout: row = quad*4+reg
            long grow = rowblk + lrow;
            int b = (int)(grow >> lev);
            int j = (int)(grow & (n - 1));
            int id = ids[b * 2046 + (n - 2) + j];
            const float* xp = xg + (gmg * 64 + id) * 256 + colblk;
#pragma unroll
            for (int nt = 0; nt < 4; nt++) {
                int lcol = nt * 16 + lr;              // C layout: col = lane&15
                float pre = acc[mt][nt][v] + xp[lcol];
                float act = (g == 4) ? tanhf(pre) : 1.f / (1.f + expf(-pre));
                lds[g * 2048 + lrow * 64 + lcol] = act;
            }
        }
    }
    __syncthreads();

    // epilogue pt 2: combine gates, children c, write h/c (and root_hidden at lev 1).
    for (int idx = threadIdx.x; idx < 2048; idx += 320) {
        int lrow = idx >> 6, lcol = idx & 63;
        long grow = rowblk + lrow;
        int gcol = colblk + lcol;
        float fl = lds[idx];
        float fr = lds[2048 + idx];
        float ig = lds[4096 + idx];
        float og = lds[6144 + idx];
        float ug = lds[8192 + idx];
        float cl = (float)Cprev[grow * 512 + gcol];
        float cr = (float)Cprev[grow * 512 + 256 + gcol];
        float cv = ig * ug + fl * cl + fr * cr;
        float hv = og * tanhf(cv);
        h_out[grow * 256 + gcol] = (__bf16)hv;
        c_out[grow * 256 + gcol] = (__bf16)cv;
        if (rh_out) rh_out[grow * 256 + gcol] = hv;
    }
}

__global__ void scores_kernel(const float* __restrict__ rh, const float* __restrict__ Ws,
                              const float* __restrict__ bs, float* __restrict__ out) {
    int b = blockIdx.x;
    int t = threadIdx.x >> 6, lane = threadIdx.x & 63;   // 3 waves, one per output
    float s = 0.f;
    for (int i = lane; i < 512; i += 64) s += rh[b * 512 + i] * Ws[i * 3 + t];
    for (int o = 32; o > 0; o >>= 1) s += __shfl_down(s, o);
    if (lane == 0) out[b * 3 + t] = s + bs[t];
}

extern "C" void kernel_launch(void* const* d_in, const int* in_sizes, int n_in,
                              void* d_out, int out_size, void* d_ws, size_t ws_size,
                              hipStream_t stream) {
    const int*   ids = (const int*)  d_in[0];
    const float* emb = (const float*)d_in[1];
    const float* W   = (const float*)d_in[2];
    const float* bW  = (const float*)d_in[3];
    const float* U   = (const float*)d_in[4];
    const float* Ws  = (const float*)d_in[5];
    const float* bs  = (const float*)d_in[6];
    float* out = (float*)d_out;   // [0:192) scores, [192:192+32768) root_hidden

    char* ws = (char*)d_ws;
    float*  xg = (float*)ws;                   //   262144 B : xg_table[4][64][256]
    __bf16* Bt = (__bf16*)(ws + 262144);       //  1310720 B : Ucat (5*256, 512)
    __bf16* h0 = (__bf16*)(ws + 1572864);      // 33554432 B : h ping (leaf-sized)
    __bf16* c0 = (__bf16*)(ws + 35127296);     // 33554432 B
    __bf16* h1 = (__bf16*)(ws + 68681728);     // 16777216 B : h pong
    __bf16* c1 = (__bf16*)(ws + 85458944);     // 16777216 B   (total 102236160 B)

    xg_prep<<<dim3(256), dim3(256), 0, stream>>>(emb, W, bW, xg);
    bt_prep<<<dim3(2560), dim3(256), 0, stream>>>(U, Bt);
    leaf_kernel<<<dim3(65536), dim3(256), 0, stream>>>(ids, xg, h0, c0);

    __bf16* hb[2] = {h0, h1};
    __bf16* cb[2] = {c0, c1};
    int cur = 0;
    for (int lev = 9; lev >= 1; lev--) {
        int M = 64 << lev;                      // B * 2^lev rows
        float* rh = (lev == 1) ? (out + 192) : nullptr;
        level_kernel<<<dim3(M / 32, 4), dim3(320), 0, stream>>>(
            hb[cur], cb[cur], Bt, xg, ids, hb[1 - cur], cb[1 - cur], rh, lev);
        cur = 1 - cur;
    }
    scores_kernel<<<dim3(64), dim3(192), 0, stream>>>(out + 192, Ws, bs, out);
}

// Round 2
// 593.284 us; speedup vs baseline: 1.3685x; 1.3685x over previous
//
#include <hip/hip_runtime.h>
#include <hip/hip_bf16.h>
#include <math.h>

// TreeLSTM on MI355X — v2: all-5-gates-per-wave, zero-LDS level kernel.
//  - xg = emb[ids] @ W collapses to a 4x64x256 table (V=64).
//  - [hl|hr] A-matrix is h_prev reinterpreted as (B*n, 512): zero movement.
//  - wave tile 64 rows x 16 cols x 5 gates; acc 20 f32x4; 9 loads : 20 MFMAs
//    per K-step with register double-buffering; gate combine in-register.

typedef __bf16 bf16x8 __attribute__((ext_vector_type(8)));
typedef float  f32x4  __attribute__((ext_vector_type(4)));

__device__ __forceinline__ float sigf(float x) {
    return 1.f / (1.f + __expf(-x));
}
__device__ __forceinline__ float tanhfast(float x) {
    // stable: expf overflows -> +inf -> 1; underflows -> 0 -> -1
    return 1.f - 2.f / (__expf(2.f * x) + 1.f);
}

__global__ void xg_prep(const float* __restrict__ emb, const float* __restrict__ W,
                        const float* __restrict__ bW, float* __restrict__ xg) {
    int g = blockIdx.x >> 6, v = blockIdx.x & 63, k = threadIdx.x;
    __shared__ float e[256];
    e[k] = emb[v * 256 + k];
    __syncthreads();
    float s = bW[g * 256 + k];
    const float* Wg = W + g * 65536 + k;
#pragma unroll 4
    for (int i = 0; i < 256; i++) s += e[i] * Wg[i * 256];
    xg[(g * 64 + v) * 256 + k] = s;
}

__global__ void bt_prep(const float* __restrict__ U, __bf16* __restrict__ Bt) {
    // Bt[g][col][kk], kk contiguous: [U[g][0][:,col] ; U[g][1][:,col]]
    int idx = blockIdx.x * 256 + threadIdx.x;   // < 5*256*512
    int g   = idx >> 17;
    int r   = idx & 131071;
    int col = r >> 9;
    int kk  = r & 511;
    int s   = kk >> 8;
    int hh  = kk & 255;
    Bt[idx] = (__bf16)U[((g * 2 + s) * 256 + hh) * 256 + col];
}

__global__ void leaf_kernel(const int* __restrict__ ids, const float* __restrict__ xg,
                            __bf16* __restrict__ h, __bf16* __restrict__ c) {
    int col = threadIdx.x;                 // 0..255
    int r0 = blockIdx.x * 32;              // 2048 blocks x 32 rows = 65536 rows
    for (int r = r0; r < r0 + 32; r++) {
        int b = r >> 10, j = r & 1023;
        int id = ids[b * 2046 + 1022 + j];
        float x1 = xg[(64  + id) * 256 + col];
        float x2 = xg[(128 + id) * 256 + col];
        float x3 = xg[(192 + id) * 256 + col];
        float ig = sigf(x1);
        float og = sigf(x2);
        float ug = tanhfast(x3);
        float cv = ig * ug;
        float hv = og * tanhfast(cv);
        h[r * 256 + col] = (__bf16)hv;
        c[r * 256 + col] = (__bf16)cv;
    }
}

// Block = 256 threads = 4 waves; wave tile = 64 rows x 16 cols x all 5 gates.
// grid = (ceil(M/256), 16 col-tiles).
__global__ __launch_bounds__(256) void level_kernel(
    const __bf16* __restrict__ A, const __bf16* __restrict__ Cprev,
    const __bf16* __restrict__ Bt, const float* __restrict__ xg,
    const int* __restrict__ ids, __bf16* __restrict__ h_out,
    __bf16* __restrict__ c_out, float* __restrict__ rh_out, int lev, int M) {
    const int wave = threadIdx.x >> 6;
    const int lane = threadIdx.x & 63;
    const int lr   = lane & 15;            // A-row / B-col within 16
    const int q    = lane >> 4;            // k-quad
    const long rowblk = ((long)blockIdx.x * 4 + wave) * 64;
    if (rowblk >= M) return;
    const int colbase = blockIdx.y * 16;   // within 256

    const __bf16* Ap = A  + (rowblk + lr) * 512 + q * 8;
    const __bf16* Bp = Bt + (long)(colbase + lr) * 512 + q * 8;

    f32x4 acc[5][4];
#pragma unroll
    for (int g = 0; g < 5; g++)
#pragma unroll
        for (int mt = 0; mt < 4; mt++) acc[g][mt] = (f32x4){0.f, 0.f, 0.f, 0.f};

    bf16x8 af[2][4], bf[2][5];
#pragma unroll
    for (int mt = 0; mt < 4; mt++) af[0][mt] = *(const bf16x8*)(Ap + mt * 8192);
#pragma unroll
    for (int g = 0; g < 5; g++)    bf[0][g]  = *(const bf16x8*)(Bp + g * 131072);

#pragma unroll
    for (int s = 0; s < 16; s++) {
        const int cur = s & 1, nxt = cur ^ 1;
        const int kn = ((s + 1) & 15) * 32;      // wraps to 0 on last (discarded)
#pragma unroll
        for (int mt = 0; mt < 4; mt++)
            af[nxt][mt] = *(const bf16x8*)(Ap + mt * 8192 + kn);
#pragma unroll
        for (int g = 0; g < 5; g++)
            bf[nxt][g]  = *(const bf16x8*)(Bp + g * 131072 + kn);
#pragma unroll
        for (int g = 0; g < 5; g++)
#pragma unroll
            for (int mt = 0; mt < 4; mt++)
                acc[g][mt] = __builtin_amdgcn_mfma_f32_16x16x32_bf16(
                    af[cur][mt], bf[cur][g], acc[g][mt], 0, 0, 0);
    }

    // In-register gate combine. C layout: col = lane&15, row = q*4 + v (+16*mt).
    const int n = 1 << lev;
    const int gcol = colbase + lr;
#pragma unroll
    for (int mt = 0; mt < 4; mt++) {
#pragma unroll
        for (int v = 0; v < 4; v++) {
            long grow = rowblk + mt * 16 + q * 4 + v;
            int b = (int)(grow >> lev);
            int j = (int)(grow & (n - 1));
            int id = ids[b * 2046 + (n - 2) + j];
            const float* xp = xg + id * 256 + gcol;
            float fl = sigf(acc[0][mt][v] + xp[0]);          // gate_map: f_l,f_r -> xg[0]
            float fr = sigf(acc[1][mt][v] + xp[0]);
            float ig = sigf(acc[2][mt][v] + xp[16384]);      // xg[1]
            float og = sigf(acc[3][mt][v] + xp[32768]);      // xg[2]
            float ug = tanhfast(acc[4][mt][v] + xp[49152]);  // xg[3]
            float cl = (float)Cprev[grow * 512 + gcol];
            float cr = (float)Cprev[grow * 512 + 256 + gcol];
            float cv = ig * ug + fl * cl + fr * cr;
            float hv = og * tanhfast(cv);
            h_out[grow * 256 + gcol] = (__bf16)hv;
            c_out[grow * 256 + gcol] = (__bf16)cv;
            if (rh_out) rh_out[grow * 256 + gcol] = hv;
        }
    }
}

__global__ void scores_kernel(const float* __restrict__ rh, const float* __restrict__ Ws,
                              const float* __restrict__ bs, float* __restrict__ out) {
    int b = blockIdx.x;
    int t = threadIdx.x >> 6, lane = threadIdx.x & 63;
    float s = 0.f;
    for (int i = lane; i < 512; i += 64) s += rh[b * 512 + i] * Ws[i * 3 + t];
    for (int o = 32; o > 0; o >>= 1) s += __shfl_down(s, o);
    if (lane == 0) out[b * 3 + t] = s + bs[t];
}

extern "C" void kernel_launch(void* const* d_in, const int* in_sizes, int n_in,
                              void* d_out, int out_size, void* d_ws, size_t ws_size,
                              hipStream_t stream) {
    const int*   ids = (const int*)  d_in[0];
    const float* emb = (const float*)d_in[1];
    const float* W   = (const float*)d_in[2];
    const float* bW  = (const float*)d_in[3];
    const float* U   = (const float*)d_in[4];
    const float* Ws  = (const float*)d_in[5];
    const float* bs  = (const float*)d_in[6];
    float* out = (float*)d_out;   // [0:192) scores, [192:) root_hidden (64x512)

    char* ws = (char*)d_ws;
    float*  xg = (float*)ws;                   //   262144 B : xg_table[4][64][256]
    __bf16* Bt = (__bf16*)(ws + 262144);       //  1310720 B : Ucat (5*256, 512)
    __bf16* h0 = (__bf16*)(ws + 1572864);      // 33554432 B : h ping (leaf-sized)
    __bf16* c0 = (__bf16*)(ws + 35127296);     // 33554432 B
    __bf16* h1 = (__bf16*)(ws + 68681728);     // 16777216 B : h pong
    __bf16* c1 = (__bf16*)(ws + 85458944);     // 16777216 B   (total 102236160 B)

    xg_prep<<<dim3(256), dim3(256), 0, stream>>>(emb, W, bW, xg);
    bt_prep<<<dim3(2560), dim3(256), 0, stream>>>(U, Bt);
    leaf_kernel<<<dim3(2048), dim3(256), 0, stream>>>(ids, xg, h0, c0);

    __bf16* hb[2] = {h0, h1};
    __bf16* cb[2] = {c0, c1};
    int cur = 0;
    for (int lev = 9; lev >= 1; lev--) {
        int M = 64 << lev;                      // B * 2^lev rows
        int gx = (M + 255) / 256;
        float* rh = (lev == 1) ? (out + 192) : nullptr;
        level_kernel<<<dim3(gx, 16), dim3(256), 0, stream>>>(
            hb[cur], cb[cur], Bt, xg, ids, hb[1 - cur], cb[1 - cur], rh, lev, M);
        cur = 1 - cur;
    }
    scores_kernel<<<dim3(64), dim3(192), 0, stream>>>(out + 192, Ws, bs, out);
}